// Round 6
// baseline (334.771 us; speedup 1.0000x reference)
//
#include <hip/hip_runtime.h>

#define QSIZE 4194304          // B*D*H*W = 64*64*1024
#define WS_E2_OFF   0          // e2[1024] f32
#define WS_ET_OFF   4096       // embT[64][1024] f32 = 262144 B

typedef float f2 __attribute__((ext_vector_type(2)));

// ---- kernel 0: fused embT transpose + e2 (numpy pairwise-8 replica) + loss zero ----
__global__ void k0_prep(const float* __restrict__ emb, float* __restrict__ embT,
                        float* __restrict__ e2, float* __restrict__ out) {
    #pragma clang fp contract(off)
    if (blockIdx.x < 256) {
        int g = blockIdx.x * 256 + threadIdx.x;   // 0..65535
        int d = g >> 10, k = g & 1023;
        embT[g] = emb[k * 64 + d];
    } else {
        #pragma unroll 1
        for (int j = 0; j < 4; ++j) {
            int k = j * 256 + threadIdx.x;
            const float* e = emb + k * 64;
            float r[8];
            #pragma unroll
            for (int q = 0; q < 8; ++q) r[q] = e[q] * e[q];
            #pragma unroll
            for (int i = 8; i < 64; i += 8) {
                #pragma unroll
                for (int q = 0; q < 8; ++q) r[q] = r[q] + e[i + q] * e[i + q];
            }
            e2[k] = ((r[0] + r[1]) + (r[2] + r[3])) + ((r[4] + r[5]) + (r[6] + r[7]));
        }
        if (threadIdx.x < 2) out[QSIZE + threadIdx.x] = 0.f;   // loss accumulators
    }
}

// ---- kernel 1: argmin (bit-exact f32 replica, v_pk_fma) + fused epilogue ----
// grid 1024 x 512 (8 waves). Block owns rows [blk*64, blk*64+64) (one b).
// Wave w scans codes [w*128, (w+1)*128) in groups of 16; lane = row-within-block.
__launch_bounds__(512, 8)
__global__ void k1_argmin(const float* __restrict__ lat, const float* __restrict__ embT,
                          const float* __restrict__ e2t, const float* __restrict__ emb,
                          float* __restrict__ out) {
    #pragma clang fp contract(off)
    __shared__ f2    xs2[32][64];   // [d/2][row] : {x[2dd], x[2dd+1]} per row, 16 KB
    __shared__ float sm1[8][64];
    __shared__ int   sbi[8][64];
    __shared__ int   sbiF[64];
    __shared__ float red[8];

    const int tid  = threadIdx.x;
    const int lane = tid & 63;
    const int w    = tid >> 6;
    const int row0 = blockIdx.x * 64;
    const int row  = row0 + lane;
    const int b    = row >> 10;
    const int hw   = row & 1023;

    // ---- stage x into LDS (coalesced global reads; wave-uniform d per iter) ----
    {
        const float* latb = lat + (size_t)b * 65536 + (row0 & 1023);
        #pragma unroll
        for (int i = 0; i < 8; ++i) {
            const int idx = i * 512 + tid;          // 0..4095
            const int d = idx >> 6, r = idx & 63;
            ((float*)&xs2[d >> 1][r])[d & 1] = latb[d * 1024 + r];
        }
    }
    __syncthreads();

    // ---- x2 = numpy pairwise-8 sum of squares for own row ----
    float x2;
    {
        float r[8];
        #pragma unroll
        for (int q = 0; q < 8; ++q) r[q] = 0.f;
        #pragma unroll
        for (int i = 0; i < 64; i += 8) {
            const f2 p0 = xs2[(i >> 1) + 0][lane];
            const f2 p1 = xs2[(i >> 1) + 1][lane];
            const f2 p2 = xs2[(i >> 1) + 2][lane];
            const f2 p3 = xs2[(i >> 1) + 3][lane];
            r[0] = r[0] + p0.x * p0.x;  r[1] = r[1] + p0.y * p0.y;
            r[2] = r[2] + p1.x * p1.x;  r[3] = r[3] + p1.y * p1.y;
            r[4] = r[4] + p2.x * p2.x;  r[5] = r[5] + p2.y * p2.y;
            r[6] = r[6] + p3.x * p3.x;  r[7] = r[7] + p3.y * p3.y;
        }
        x2 = ((r[0] + r[1]) + (r[2] + r[3])) + ((r[4] + r[5]) + (r[6] + r[7]));
    }

    // ---- main loop: 16 codes per group as 8 float2 chains (v_pk_fma_f32) ----
    const int kbase = __builtin_amdgcn_readfirstlane(w) << 7;   // 128 codes/wave
    float m1 = 3.4e38f;
    int   bi = kbase;
    #pragma unroll 1
    for (int g = 0; g < 8; ++g) {
        const int k0c = kbase + (g << 4);
        f2 c2[8];
        #pragma unroll
        for (int j = 0; j < 8; ++j) c2[j] = (f2){0.f, 0.f};
        #pragma unroll
        for (int dd = 0; dd < 32; ++dd) {
            const f2 xv = xs2[dd][lane];
            const f2* __restrict__ e0 = (const f2*)(embT + (dd << 11) + k0c); // row 2dd
            const f2 xl = {xv.x, xv.x};
            #pragma unroll
            for (int j = 0; j < 8; ++j) c2[j] = __builtin_elementwise_fma(e0[j], xl, c2[j]);
            const f2* __restrict__ e1 = e0 + 512;                             // row 2dd+1
            const f2 xh = {xv.y, xv.y};
            #pragma unroll
            for (int j = 0; j < 8; ++j) c2[j] = __builtin_elementwise_fma(e1[j], xh, c2[j]);
        }
        #pragma unroll
        for (int j = 0; j < 8; ++j) {
            const float ta = x2 + e2t[k0c + 2 * j];
            const float da = ta - 2.0f * c2[j].x;            // 2*c exact (pow2)
            if (da < m1) { m1 = da; bi = k0c + 2 * j; }      // strict <, ascending k
            const float tb = x2 + e2t[k0c + 2 * j + 1];
            const float db = tb - 2.0f * c2[j].y;
            if (db < m1) { m1 = db; bi = k0c + 2 * j + 1; }
        }
    }
    sm1[w][lane] = m1;
    sbi[w][lane] = bi;
    __syncthreads();

    // ---- wave 0: merge 8 chunks (ascending k, strict < keeps first index) ----
    if (w == 0) {
        float M1 = sm1[0][lane];
        int   BI = sbi[0][lane];
        #pragma unroll
        for (int ww = 1; ww < 8; ++ww) {
            const float a = sm1[ww][lane];
            if (a < M1) { M1 = a; BI = sbi[ww][lane]; }
        }
        sbiF[lane] = BI;
        out[QSIZE + 2 + row] = (float)BI;            // index as float, coalesced
    }
    __syncthreads();

    // ---- fused epilogue: wave w writes d in [w*8, w*8+8) for all rows ----
    {
        const float* xg = lat + (size_t)b * 65536 + hw;
        const int BI = sbiF[lane];
        const float* er = emb + BI * 64 + w * 8;     // 32B-aligned per-lane gather
        float sq = 0.f;
        #pragma unroll
        for (int j4 = 0; j4 < 2; ++j4) {
            const float4 q4 = *(const float4*)(er + j4 * 4);
            #pragma unroll
            for (int j2 = 0; j2 < 4; ++j2) {
                const int d = w * 8 + j4 * 4 + j2;
                const float xv  = xg[d * 1024];
                const float qv  = (&q4.x)[j2];
                const float qmx = qv - xv;
                out[(size_t)b * 65536 + d * 1024 + hw] = xv + qmx;  // straight-through
                sq = __builtin_fmaf(qmx, qmx, sq);
            }
        }
        #pragma unroll
        for (int off = 32; off > 0; off >>= 1) sq += __shfl_down(sq, off, 64);
        if (lane == 0) red[w] = sq;
    }
    __syncthreads();
    if (tid == 0) {
        const float p = (((red[0] + red[1]) + (red[2] + red[3]))
                       + ((red[4] + red[5]) + (red[6] + red[7]))) * (1.0f / 4194304.0f);
        atomicAdd(&out[QSIZE],     p);   // commitment_loss
        atomicAdd(&out[QSIZE + 1], p);   // embedding_loss
    }
}

extern "C" void kernel_launch(void* const* d_in, const int* in_sizes, int n_in,
                              void* d_out, int out_size, void* d_ws, size_t ws_size,
                              hipStream_t stream) {
    const float* lat = (const float*)d_in[0];   // [64,64,32,32] f32
    const float* emb = (const float*)d_in[1];   // [1024,64] f32
    float* out  = (float*)d_out;
    char*  ws   = (char*)d_ws;
    float* e2t  = (float*)(ws + WS_E2_OFF);
    float* embT = (float*)(ws + WS_ET_OFF);

    hipLaunchKernelGGL(k0_prep,   dim3(257),  dim3(256), 0, stream, emb, embT, e2t, out);
    hipLaunchKernelGGL(k1_argmin, dim3(1024), dim3(512), 0, stream, lat, embT, e2t, emb, out);
}

// Round 8
// 183.640 us; speedup vs baseline: 1.8230x; 1.8230x over previous
//
#include <hip/hip_runtime.h>

#define QSIZE 4194304          // B*D*H*W = 64*64*1024
#define WS_E2_OFF   0          // e2[1024] f32
#define WS_ET_OFF   4096       // embT[64][1024] f32 = 262144 B

// ---- kernel 0: fused embT transpose + e2 (numpy pairwise-8 replica) + loss zero ----
__global__ void k0_prep(const float* __restrict__ emb, float* __restrict__ embT,
                        float* __restrict__ e2, float* __restrict__ out) {
    #pragma clang fp contract(off)
    if (blockIdx.x < 256) {
        int g = blockIdx.x * 256 + threadIdx.x;   // 0..65535
        int d = g >> 10, k = g & 1023;
        embT[g] = emb[k * 64 + d];
    } else {
        #pragma unroll 1
        for (int j = 0; j < 4; ++j) {
            int k = j * 256 + threadIdx.x;
            const float* e = emb + k * 64;
            float r[8];
            #pragma unroll
            for (int q = 0; q < 8; ++q) r[q] = e[q] * e[q];
            #pragma unroll
            for (int i = 8; i < 64; i += 8) {
                #pragma unroll
                for (int q = 0; q < 8; ++q) r[q] = r[q] + e[i + q] * e[i + q];
            }
            e2[k] = ((r[0] + r[1]) + (r[2] + r[3])) + ((r[4] + r[5]) + (r[6] + r[7]));
        }
        if (threadIdx.x < 2) out[QSIZE + threadIdx.x] = 0.f;   // loss accumulators
    }
}

// ---- kernel 1: argmin (bit-exact f32 replica) + fused epilogue ----
// grid 1024 x 512 (8 waves). Block owns rows [blk*64, blk*64+64) (one b).
// Wave w scans codes [w*128, (w+1)*128) in groups of 16; lane = row-within-block.
// Round-4-proven codegen: scalar float c[16], s_load embedding, unroll 2 on dd.
__launch_bounds__(512, 8)
__global__ void k1_argmin(const float* __restrict__ lat, const float* __restrict__ embT,
                          const float* __restrict__ e2t, const float* __restrict__ emb,
                          float* __restrict__ out) {
    #pragma clang fp contract(off)
    __shared__ float2 xs2[32][64];  // [d/2][row] : {x[2dd], x[2dd+1]} per row, 16 KB
    __shared__ float sm1[8][64];
    __shared__ int   sbi[8][64];
    __shared__ int   sbiF[64];
    __shared__ float red[8];

    const int tid  = threadIdx.x;
    const int lane = tid & 63;
    const int w    = tid >> 6;
    const int row0 = blockIdx.x * 64;
    const int row  = row0 + lane;
    const int b    = row >> 10;
    const int hw   = row & 1023;

    // ---- stage x into LDS (coalesced global reads; wave-uniform d per iter) ----
    {
        const float* latb = lat + (size_t)b * 65536 + (row0 & 1023);
        #pragma unroll
        for (int i = 0; i < 8; ++i) {
            const int idx = i * 512 + tid;          // 0..4095
            const int d = idx >> 6, r = idx & 63;
            ((float*)&xs2[d >> 1][r])[d & 1] = latb[d * 1024 + r];
        }
    }
    __syncthreads();

    // ---- x2 = numpy pairwise-8 sum of squares for own row ----
    float x2;
    {
        float r[8];
        #pragma unroll
        for (int j = 0; j < 8; ++j) {
            const float v = ((const float*)&xs2[j >> 1][lane])[j & 1];
            r[j] = v * v;
        }
        #pragma unroll
        for (int i = 8; i < 64; i += 8) {
            #pragma unroll
            for (int j = 0; j < 8; ++j) {
                const float v = ((const float*)&xs2[(i + j) >> 1][lane])[(i + j) & 1];
                r[j] = r[j] + v * v;
            }
        }
        x2 = ((r[0] + r[1]) + (r[2] + r[3])) + ((r[4] + r[5]) + (r[6] + r[7]));
    }

    // ---- main loop: 16 codes per group, e via wave-uniform scalar loads ----
    const int kbase = __builtin_amdgcn_readfirstlane(w) << 7;   // 128 codes/wave
    float m1 = 3.4e38f;
    int   bi = kbase;
    #pragma unroll 1
    for (int g = 0; g < 8; ++g) {
        const int k0 = kbase + (g << 4);
        const float* __restrict__ ed  = embT + k0;   // column block [*, k0..k0+15]
        const float* __restrict__ e2g = e2t + k0;
        float c[16];
        #pragma unroll
        for (int j = 0; j < 16; ++j) c[j] = 0.f;
        #pragma unroll 2
        for (int dd = 0; dd < 32; ++dd) {
            const float2 xv = xs2[dd][lane];
            const float* e0 = ed + (dd << 11);       // row 2dd of embT
            #pragma unroll
            for (int j = 0; j < 16; ++j) c[j] = __builtin_fmaf(xv.x, e0[j], c[j]);
            const float* e1 = e0 + 1024;             // row 2dd+1
            #pragma unroll
            for (int j = 0; j < 16; ++j) c[j] = __builtin_fmaf(xv.y, e1[j], c[j]);
        }
        #pragma unroll
        for (int j = 0; j < 16; ++j) {
            const float t  = x2 + e2g[j];
            const float dv = t - 2.0f * c[j];        // 2*c exact (power of two)
            if (dv < m1) { m1 = dv; bi = k0 + j; }   // strict <, ascending k
        }
    }
    sm1[w][lane] = m1;
    sbi[w][lane] = bi;
    __syncthreads();

    // ---- wave 0: merge 8 chunks (ascending k, strict < keeps first index) ----
    if (w == 0) {
        float M1 = sm1[0][lane];
        int   BI = sbi[0][lane];
        #pragma unroll
        for (int ww = 1; ww < 8; ++ww) {
            const float a = sm1[ww][lane];
            if (a < M1) { M1 = a; BI = sbi[ww][lane]; }
        }
        sbiF[lane] = BI;
        out[QSIZE + 2 + row] = (float)BI;            // index as float, coalesced
    }
    __syncthreads();

    // ---- fused epilogue: wave w writes d in [w*8, w*8+8) for all rows ----
    {
        const float* xg = lat + (size_t)b * 65536 + hw;
        const int BI = sbiF[lane];
        const float* er = emb + BI * 64 + w * 8;     // 32B-aligned per-lane gather
        float sq = 0.f;
        #pragma unroll
        for (int j4 = 0; j4 < 2; ++j4) {
            const float4 q4 = *(const float4*)(er + j4 * 4);
            #pragma unroll
            for (int j2 = 0; j2 < 4; ++j2) {
                const int d = w * 8 + j4 * 4 + j2;
                const float xv  = xg[d * 1024];
                const float qv  = (&q4.x)[j2];
                const float qmx = qv - xv;
                out[(size_t)b * 65536 + d * 1024 + hw] = xv + qmx;  // straight-through
                sq = __builtin_fmaf(qmx, qmx, sq);
            }
        }
        #pragma unroll
        for (int off = 32; off > 0; off >>= 1) sq += __shfl_down(sq, off, 64);
        if (lane == 0) red[w] = sq;
    }
    __syncthreads();
    if (tid == 0) {
        const float p = (((red[0] + red[1]) + (red[2] + red[3]))
                       + ((red[4] + red[5]) + (red[6] + red[7]))) * (1.0f / 4194304.0f);
        atomicAdd(&out[QSIZE],     p);   // commitment_loss
        atomicAdd(&out[QSIZE + 1], p);   // embedding_loss
    }
}

extern "C" void kernel_launch(void* const* d_in, const int* in_sizes, int n_in,
                              void* d_out, int out_size, void* d_ws, size_t ws_size,
                              hipStream_t stream) {
    const float* lat = (const float*)d_in[0];   // [64,64,32,32] f32
    const float* emb = (const float*)d_in[1];   // [1024,64] f32
    float* out  = (float*)d_out;
    char*  ws   = (char*)d_ws;
    float* e2t  = (float*)(ws + WS_E2_OFF);
    float* embT = (float*)(ws + WS_ET_OFF);

    hipLaunchKernelGGL(k0_prep,   dim3(257),  dim3(256), 0, stream, emb, embT, e2t, out);
    hipLaunchKernelGGL(k1_argmin, dim3(1024), dim3(512), 0, stream, lat, embT, e2t, emb, out);
}